// Round 2
// baseline (573.666 us; speedup 1.0000x reference)
//
#include <hip/hip_runtime.h>

typedef unsigned short ushort_t;
typedef unsigned int uint32;
typedef __attribute__((ext_vector_type(8))) short short8;
typedef __attribute__((ext_vector_type(4))) float float4v;

#define LDS_S 136  // padded row stride (bf16 elems) for Wt; 136*2B=272B => 16B-aligned rows

__device__ inline float bf16_lo(uint32 v) { return __uint_as_float(v << 16); }
__device__ inline float bf16_hi(uint32 v) { return __uint_as_float(v & 0xFFFF0000u); }

__device__ inline ushort_t f32_to_bf16(float f) {
    uint32 u = __float_as_uint(f);
    uint32 r = u + 0x7FFFu + ((u >> 16) & 1u);   // round-to-nearest-even
    return (ushort_t)(r >> 16);
}

// ---------------- graph preprocessing ----------------

__global__ __launch_bounds__(256) void hist_kernel(const int* __restrict__ er,
                                                   const int* __restrict__ ec,
                                                   int* __restrict__ degcnt,
                                                   int* __restrict__ colcnt, int E) {
    int e = blockIdx.x * 256 + threadIdx.x;
    if (e < E) {
        atomicAdd(&degcnt[er[e]], 1);
        atomicAdd(&colcnt[ec[e]], 1);
    }
}

__global__ __launch_bounds__(256) void dis_kernel(const int* __restrict__ degcnt,
                                                  float* __restrict__ dis, int N) {
    int i = blockIdx.x * 256 + threadIdx.x;
    if (i < N) dis[i] = rsqrtf((float)(degcnt[i] + 1));  // +1 self loop; always > 0
}

// single-block exclusive scan over colcnt -> rowptr[0..N], rowptr[N] = E
__global__ __launch_bounds__(1024) void scan_kernel(const int* __restrict__ cnt,
                                                    int* __restrict__ rowptr, int N) {
    __shared__ int part[1024];
    int tid = threadIdx.x;
    int per = (N + 1023) / 1024;
    int start = tid * per;
    int end = min(start + per, N);
    int s = 0;
    for (int i = start; i < end; i++) s += cnt[i];
    part[tid] = s;
    __syncthreads();
    for (int off = 1; off < 1024; off <<= 1) {
        int v = (tid >= off) ? part[tid - off] : 0;
        __syncthreads();
        part[tid] += v;
        __syncthreads();
    }
    int run = part[tid] - s;  // exclusive
    for (int i = start; i < end; i++) { rowptr[i] = run; run += cnt[i]; }
    if (tid == 1023) rowptr[N] = part[1023];
}

__global__ __launch_bounds__(256) void fill_kernel(const int* __restrict__ er,
                                                   const int* __restrict__ ec,
                                                   const int* __restrict__ rowptr,
                                                   int* __restrict__ fillcnt,
                                                   int* __restrict__ csr_src, int E) {
    int e = blockIdx.x * 256 + threadIdx.x;
    if (e < E) {
        int c = ec[e];
        int pos = rowptr[c] + atomicAdd(&fillcnt[c], 1);
        csr_src[pos] = er[e];
    }
}

// ---------------- dense transform: H = X @ W  (f32 in, bf16 MFMA, bf16 out, f32 accum) -------
// Block = 256 threads (4 waves), M-tile = 64 rows (16 rows/wave), K = 128.
__global__ __launch_bounds__(256) void gemm_xw(const float* __restrict__ X,
                                               const float* __restrict__ W,
                                               ushort_t* __restrict__ H, int M) {
    __shared__ ushort_t Wt[128 * LDS_S];  // Wt[n][k] = bf16(W[k][n]), padded stride
    const int tid = threadIdx.x;
    for (int idx = tid; idx < 128 * 128; idx += 256) {
        int k = idx >> 7, nn = idx & 127;
        Wt[nn * LDS_S + k] = f32_to_bf16(W[idx]);
    }
    __syncthreads();

    const int lane = tid & 63, wave = tid >> 6;
    const int quad = lane >> 4, r = lane & 15;
    int arow = blockIdx.x * 64 + wave * 16 + r;        // A-operand row (m = lane&15)
    if (arow >= M) arow = M - 1;                        // clamp; OOB results discarded at store
    const float* xrow = X + (size_t)arow * 128;

    float4v acc[8];
#pragma unroll
    for (int i = 0; i < 8; i++) acc[i] = (float4v)(0.0f);

#pragma unroll
    for (int kk = 0; kk < 4; kk++) {
        const int k0 = kk * 32 + quad * 8;             // a[j] = A[m][k0+j]
        float4 x0 = *(const float4*)(xrow + k0);
        float4 x1 = *(const float4*)(xrow + k0 + 4);
        short8 a;
        a[0] = (short)f32_to_bf16(x0.x); a[1] = (short)f32_to_bf16(x0.y);
        a[2] = (short)f32_to_bf16(x0.z); a[3] = (short)f32_to_bf16(x0.w);
        a[4] = (short)f32_to_bf16(x1.x); a[5] = (short)f32_to_bf16(x1.y);
        a[6] = (short)f32_to_bf16(x1.z); a[7] = (short)f32_to_bf16(x1.w);
#pragma unroll
        for (int nt = 0; nt < 8; nt++) {
            short8 b = *(const short8*)(&Wt[(nt * 16 + r) * LDS_S + k0]);  // b[j]=W[k0+j][n]
            acc[nt] = __builtin_amdgcn_mfma_f32_16x16x32_bf16(a, b, acc[nt], 0, 0, 0);
        }
    }

    // C/D layout: col = lane&15 (=r), row-in-tile = quad*4 + reg
    const int orow0 = blockIdx.x * 64 + wave * 16 + quad * 4;
#pragma unroll
    for (int reg = 0; reg < 4; reg++) {
        int gr = orow0 + reg;
        if (gr < M) {
            ushort_t* hp = H + (size_t)gr * 128 + r;
#pragma unroll
            for (int nt = 0; nt < 8; nt++) hp[nt * 16] = f32_to_bf16(acc[nt][reg]);
        }
    }
}

// ---------------- aggregation: out[i] = dis[i]*(sum_{e:col=i} dis[src]*h[src]) + dis[i]^2*h[i] + b
// One wave per destination node; each lane owns 2 channels (one 4B load per h-row).
__global__ __launch_bounds__(256) void agg_kernel(const ushort_t* __restrict__ h,
                                                  const float* __restrict__ dis,
                                                  const int* __restrict__ rowptr,
                                                  const int* __restrict__ csr_src,
                                                  const float* __restrict__ bias,
                                                  float* __restrict__ out,
                                                  int N, int do_relu) {
    const int wave = threadIdx.x >> 6, lane = threadIdx.x & 63;
    const int node = blockIdx.x * 4 + wave;
    if (node >= N) return;
    const int c0 = lane * 2;

    float a0 = 0.0f, a1 = 0.0f;
    int e = rowptr[node];
    const int end = rowptr[node + 1];
    for (; e + 2 <= end; e += 2) {  // unroll x2 for load ILP
        int s0 = csr_src[e], s1 = csr_src[e + 1];
        uint32 v0 = *(const uint32*)(h + (size_t)s0 * 128 + c0);
        uint32 v1 = *(const uint32*)(h + (size_t)s1 * 128 + c0);
        float w0 = dis[s0], w1 = dis[s1];
        a0 += w0 * bf16_lo(v0) + w1 * bf16_lo(v1);
        a1 += w0 * bf16_hi(v0) + w1 * bf16_hi(v1);
    }
    if (e < end) {
        int s0 = csr_src[e];
        uint32 v0 = *(const uint32*)(h + (size_t)s0 * 128 + c0);
        float w0 = dis[s0];
        a0 += w0 * bf16_lo(v0);
        a1 += w0 * bf16_hi(v0);
    }

    const float di = dis[node];
    uint32 vs = *(const uint32*)(h + (size_t)node * 128 + c0);
    float2 bv = *(const float2*)(bias + c0);
    a0 = di * a0 + di * di * bf16_lo(vs) + bv.x;
    a1 = di * a1 + di * di * bf16_hi(vs) + bv.y;
    if (do_relu) { a0 = fmaxf(a0, 0.0f); a1 = fmaxf(a1, 0.0f); }

    *(float2*)(out + (size_t)node * 128 + c0) = make_float2(a0, a1);
}

// ---------------- launch ----------------

extern "C" void kernel_launch(void* const* d_in, const int* in_sizes, int n_in,
                              void* d_out, int out_size, void* d_ws, size_t ws_size,
                              hipStream_t stream) {
    const float* x  = (const float*)d_in[0];   // [N,128] f32
    const int*   ei = (const int*)d_in[1];     // [2,E] int32
    const float* W1 = (const float*)d_in[2];   // [128,128] f32
    const float* b1 = (const float*)d_in[3];   // [128] f32
    const float* W2 = (const float*)d_in[4];
    const float* b2 = (const float*)d_in[5];
    float* out = (float*)d_out;                // [N,128] f32

    const int N = in_sizes[0] / 128;
    const int E = in_sizes[1] / 2;
    const int* er = ei;        // sources (gathered)
    const int* ec = ei + E;    // destinations (scattered)

    char* ws = (char*)d_ws;
    size_t off = 0;
    auto alloc = [&](size_t b) { size_t o = off; off += (b + 255) & ~(size_t)255; return o; };
    size_t o_deg  = alloc((size_t)N * 4);
    size_t o_col  = alloc((size_t)N * 4);
    size_t o_fill = alloc((size_t)N * 4);
    size_t cnt_bytes = off;                    // zero the three counter arrays in one memset
    size_t o_rp   = alloc((size_t)(N + 1) * 4);
    size_t o_dis  = alloc((size_t)N * 4);
    size_t o_csr  = alloc((size_t)E * 4);
    size_t o_h    = alloc((size_t)N * 128 * 2);
    (void)ws_size;

    int*   deg  = (int*)(ws + o_deg);
    int*   col  = (int*)(ws + o_col);
    int*   fcnt = (int*)(ws + o_fill);
    int*   rp   = (int*)(ws + o_rp);
    float* dis  = (float*)(ws + o_dis);
    int*   csr  = (int*)(ws + o_csr);
    ushort_t* h = (ushort_t*)(ws + o_h);

    hipMemsetAsync(ws, 0, cnt_bytes, stream);

    hist_kernel<<<(E + 255) / 256, 256, 0, stream>>>(er, ec, deg, col, E);
    dis_kernel<<<(N + 255) / 256, 256, 0, stream>>>(deg, dis, N);
    scan_kernel<<<1, 1024, 0, stream>>>(col, rp, N);
    fill_kernel<<<(E + 255) / 256, 256, 0, stream>>>(er, ec, rp, fcnt, csr, E);

    // layer 1: h = bf16(x@W1) ; d_out = relu(agg(h) + b1)   (d_out doubles as f32 scratch)
    gemm_xw<<<(N + 63) / 64, 256, 0, stream>>>(x, W1, h, N);
    agg_kernel<<<(N + 3) / 4, 256, 0, stream>>>(h, dis, rp, csr, b1, out, N, 1);

    // layer 2: h = bf16(d_out@W2) ; d_out = agg(h) + b2
    gemm_xw<<<(N + 63) / 64, 256, 0, stream>>>(out, W2, h, N);
    agg_kernel<<<(N + 3) / 4, 256, 0, stream>>>(h, dis, rp, csr, b2, out, N, 0);
}